// Round 7
// baseline (1889.651 us; speedup 1.0000x reference)
//
#include <hip/hip_runtime.h>
#include <hip/hip_bf16.h>

// Sizes: S=128, B=64, N=64, K=16, P=48, M=32
// Outputs: A [S,B,64,64] (C=4096), Bo [S,B,64,32] (C=2048), Cc [S,B,48,64] (C=3072)
#define SB 8192   // S*B

typedef float f4 __attribute__((ext_vector_type(4)));  // clang-native vec4

__device__ __forceinline__ float fsig(float x) {
    return __builtin_amdgcn_rcpf(1.f + __expf(-x));
}
__device__ __forceinline__ float ftanh(float x) {
    // tanh(x) = 1 - 2/(exp(2x)+1); correct limits at +-inf via rcp(inf)=0
    return fmaf(-2.f, __builtin_amdgcn_rcpf(1.f + __expf(2.f * x)), 1.f);
}

// ---------------------------------------------------------------------------
// Kernel 1: xg[row][t*4+q] = dot(x[row], W_ih[q*16+t]) + b_ih[g] + b_hh[g]
// Gate-interleaved layout so the scan loads one float4 per step.
// Block 0 also zeroes the progress flags for the fused kernel.
// ---------------------------------------------------------------------------
__global__ __launch_bounds__(256) void xgate_kernel(
    const float* __restrict__ x,    // [8192][64]
    const float* __restrict__ Wih,  // [64][64]
    const float* __restrict__ bih,  // [64]
    const float* __restrict__ bhh,  // [64]
    float* __restrict__ xg,         // [8192][16][4] gate-interleaved
    unsigned int* __restrict__ flags)
{
    __shared__ float xs[4][64];
    const int tid = threadIdx.x;
    if (blockIdx.x == 0 && tid < 16) flags[tid * 32] = 0u;  // one flag per cacheline

    const int rl  = tid >> 6;
    const int g   = tid & 63;           // weight row: g = q*16 + t
    const size_t rowBase = (size_t)blockIdx.x * 4;

    xs[rl][g] = x[rowBase * 64 + tid];
    __syncthreads();

    const float* xr = xs[rl];
    float acc = bih[g] + bhh[g];
#pragma unroll
    for (int n = 0; n < 64; n += 4) {
        f4 wv = *reinterpret_cast<const f4*>(&Wih[g * 64 + n]);
        acc = fmaf(xr[n + 0], wv.x, acc);
        acc = fmaf(xr[n + 1], wv.y, acc);
        acc = fmaf(xr[n + 2], wv.z, acc);
        acc = fmaf(xr[n + 3], wv.w, acc);
    }
    // remap: unit t = g&15, gate q = g>>4  ->  slot t*4+q
    xg[(rowBase + rl) * 64 + (g & 15) * 4 + (g >> 4)] = acc;
}

// ---------------------------------------------------------------------------
// Kernel 2 (fused producer-consumer):
//  blocks 0..15   : LSTM scan (wave 0 only; shfl h-broadcast, no barriers).
//                   Publishes w in chunks of 8 steps via RELEASE atomicAdd.
//  blocks 16..1023: wsum tiles in s-order; ACQUIRE-spin on the chunk flag,
//                   stage w[s] to LDS (vector loads), 64 rows of FMA+stores.
// Grid = 1024 blocks, launch_bounds(256,4) -> 4 blocks/CU -> all co-resident.
// ---------------------------------------------------------------------------
__global__ __launch_bounds__(256, 4) void fused_scan_wsum_kernel(
    const float* __restrict__ xg,   // [S][B][16][4]
    const float* __restrict__ Whh,  // [64][16]
    float* __restrict__ w,          // [S][B][16]
    unsigned int* __restrict__ flags,
    const float* __restrict__ As, const float* __restrict__ Bs,
    const float* __restrict__ Cs,
    float* __restrict__ outA, float* __restrict__ outB, float* __restrict__ outC)
{
    __shared__ f4 lds4[256];        // 64 rows x 4 f4 of w (consumer path)
    const int tid = threadIdx.x;
    const int bid = blockIdx.x;

    if (bid < 16) {
        // ---------------- producer: LSTM scan ----------------
        if (tid >= 64) return;      // wave 0 only; no barriers below
        const int t  = tid & 15;
        const int b4 = tid >> 4;
        const int b  = bid * 4 + b4;

        float wi[16], wf[16], wg[16], wo[16];
#pragma unroll
        for (int k = 0; k < 16; ++k) {
            wi[k] = Whh[(0 * 16 + t) * 16 + k];
            wf[k] = Whh[(1 * 16 + t) * 16 + k];
            wg[k] = Whh[(2 * 16 + t) * 16 + k];
            wo[k] = Whh[(3 * 16 + t) * 16 + k];
        }

        const f4* xp = reinterpret_cast<const f4*>(xg) + b * 16 + t;
        f4 xv = xp[0];
        float h = 0.f, c = 0.f;
        for (int s = 0; s < 128; ++s) {
            f4 nx = (s < 127) ? xp[(size_t)(s + 1) * 1024] : (f4)0.f;
            float ai = xv.x, af = xv.y, ag = xv.z, ao = xv.w;
#pragma unroll
            for (int k = 0; k < 16; ++k) {
                float hk = __shfl(h, k, 16);
                ai = fmaf(hk, wi[k], ai);
                af = fmaf(hk, wf[k], af);
                ag = fmaf(hk, wg[k], ag);
                ao = fmaf(hk, wo[k], ao);
            }
            float ig = fsig(ai), fg = fsig(af), og = fsig(ao);
            float gt = ftanh(ag);
            c = fg * c + ig * gt;
            h = og * ftanh(c);
            w[((size_t)s * 64 + b) * 16 + t] = h;
            xv = nx;
            if ((s & 7) == 7 && tid == 0) {
                // release: fences this wave's w stores for steps s-7..s
                __hip_atomic_fetch_add(&flags[(s >> 3) * 32], 1u,
                                       __ATOMIC_RELEASE, __HIP_MEMORY_SCOPE_AGENT);
            }
        }
        return;
    }

    // ---------------- consumers: weighted sums ----------------
    const int j  = bid - 16;                  // 0..1007
    int T        = (j < 144) ? 2 * j : 144 + j;   // tiles in s-order
    const int nt = (j < 144) ? 2 : 1;         // first 144 blocks: 2 early tiles

    for (int it = 0; it < nt; ++it, ++T) {
        const int s  = T / 9;
        const int ct = T % 9;

        const float* M; float* o; int C, cto;
        if (ct < 4)      { M = As; o = outA; C = 4096; cto = ct; }
        else if (ct < 6) { M = Bs; o = outB; C = 2048; cto = ct - 4; }
        else             { M = Cs; o = outC; C = 3072; cto = ct - 6; }
        const int i4 = cto * 1024 + tid * 4;

        // matrix slice into registers BEFORE the wait (hides load latency)
        f4 m[16];
#pragma unroll
        for (int k = 0; k < 16; ++k)
            m[k] = *reinterpret_cast<const f4*>(&M[(size_t)k * C + i4]);

        // wait for w chunk (lane 0 of each wave -> per-wave acquire)
        const int chunk = s >> 3;
        if ((tid & 63) == 0) {
            while (__hip_atomic_load(&flags[chunk * 32],
                                     __ATOMIC_ACQUIRE, __HIP_MEMORY_SCOPE_AGENT) < 16u)
                __builtin_amdgcn_s_sleep(8);
        }
        __syncthreads();

        // stage w[s] (64 rows x 16) to LDS via vector loads
        lds4[tid] = reinterpret_cast<const f4*>(w)[s * 256 + tid];
        __syncthreads();

        float* op = o + (size_t)(s * 64) * C + i4;
#pragma unroll 2
        for (int r = 0; r < 64; ++r) {
            f4 w0 = lds4[r * 4 + 0];    // broadcast ds_read_b128
            f4 w1 = lds4[r * 4 + 1];
            f4 w2 = lds4[r * 4 + 2];
            f4 w3 = lds4[r * 4 + 3];
            f4 acc = (f4)0.f;
#pragma unroll
            for (int q = 0; q < 4; ++q) acc += w0[q] * m[q + 0];
#pragma unroll
            for (int q = 0; q < 4; ++q) acc += w1[q] * m[q + 4];
#pragma unroll
            for (int q = 0; q < 4; ++q) acc += w2[q] * m[q + 8];
#pragma unroll
            for (int q = 0; q < 4; ++q) acc += w3[q] * m[q + 12];
            *reinterpret_cast<f4*>(op) = acc;
            op += C;
        }
        __syncthreads();   // protect LDS before restaging (nt==2 blocks)
    }
}

// ---------------------------------------------------------------------------
extern "C" void kernel_launch(void* const* d_in, const int* in_sizes, int n_in,
                              void* d_out, int out_size, void* d_ws, size_t ws_size,
                              hipStream_t stream) {
    const float* state = (const float*)d_in[0];
    const float* W_ih  = (const float*)d_in[1];
    const float* W_hh  = (const float*)d_in[2];
    const float* b_ih  = (const float*)d_in[3];
    const float* b_hh  = (const float*)d_in[4];
    const float* As    = (const float*)d_in[5];
    const float* Bs    = (const float*)d_in[6];
    const float* Cs    = (const float*)d_in[7];
    float* out = (float*)d_out;

    float* xg = (float*)d_ws;                     // 8192*64 floats = 2 MiB
    float* w  = xg + (size_t)SB * 64;             // 8192*16 floats = 512 KiB
    unsigned int* flags = (unsigned int*)(w + (size_t)SB * 16);  // 16 flags, 128B apart

    float* outA = out;
    float* outB = out + (size_t)SB * 4096;
    float* outC = out + (size_t)SB * 4096 + (size_t)SB * 2048;

    xgate_kernel<<<SB / 4, 256, 0, stream>>>(state, W_ih, b_ih, b_hh, xg, flags);
    fused_scan_wsum_kernel<<<1024, 256, 0, stream>>>(xg, W_hh, w, flags,
                                                     As, Bs, Cs, outA, outB, outC);
}

// Round 8
// 136.520 us; speedup vs baseline: 13.8415x; 13.8415x over previous
//
#include <hip/hip_runtime.h>
#include <hip/hip_bf16.h>

// Sizes: S=128, B=64, N=64, K=16, P=48, M=32
// Outputs: A [S,B,64,64] (C=4096), Bo [S,B,64,32] (C=2048), Cc [S,B,48,64] (C=3072)
#define SB 8192   // S*B

typedef float f4 __attribute__((ext_vector_type(4)));  // clang-native vec4

__device__ __forceinline__ float fsig(float x) {
    return __builtin_amdgcn_rcpf(1.f + __expf(-x));
}
__device__ __forceinline__ float ftanh(float x) {
    // tanh(x) = 1 - 2/(exp(2x)+1); correct limits at +-inf via rcp(inf)=0
    return fmaf(-2.f, __builtin_amdgcn_rcpf(1.f + __expf(2.f * x)), 1.f);
}

// ---------------------------------------------------------------------------
// Kernel 1: xg[row][t*4+q] = dot(x[row], W_ih[q*16+t]) + b_ih[g] + b_hh[g]
// Gate-interleaved layout so the scan loads one float4 per step.
// ---------------------------------------------------------------------------
__global__ __launch_bounds__(256) void xgate_kernel(
    const float* __restrict__ x,    // [8192][64]
    const float* __restrict__ Wih,  // [64][64]
    const float* __restrict__ bih,  // [64]
    const float* __restrict__ bhh,  // [64]
    float* __restrict__ xg)         // [8192][16][4] gate-interleaved
{
    __shared__ float xs[4][64];
    const int tid = threadIdx.x;
    const int rl  = tid >> 6;
    const int g   = tid & 63;           // weight row: g = q*16 + t
    const size_t rowBase = (size_t)blockIdx.x * 4;

    xs[rl][g] = x[rowBase * 64 + tid];
    __syncthreads();

    const float* xr = xs[rl];
    float acc = bih[g] + bhh[g];
#pragma unroll
    for (int n = 0; n < 64; n += 4) {
        f4 wv = *reinterpret_cast<const f4*>(&Wih[g * 64 + n]);
        acc = fmaf(xr[n + 0], wv.x, acc);
        acc = fmaf(xr[n + 1], wv.y, acc);
        acc = fmaf(xr[n + 2], wv.z, acc);
        acc = fmaf(xr[n + 3], wv.w, acc);
    }
    // remap: unit t = g&15, gate q = g>>4  ->  slot t*4+q
    xg[(rowBase + rl) * 64 + (g & 15) * 4 + (g >> 4)] = acc;
}

// ---------------------------------------------------------------------------
// LSTM scan chunk (steps [s0,s1)). One wave per block, thread owns (b, t).
// h broadcast via width-16 shfl; no LDS, no barriers. h,c carried across
// chunks through hc[] in workspace (kernel boundary orders the handoff).
// ---------------------------------------------------------------------------
__device__ __forceinline__ void scan_chunk(
    const float* __restrict__ xg,   // [S][B][16][4]
    const float* __restrict__ Whh,  // [64][16]
    float* __restrict__ w,          // [S][B][16]
    float* __restrict__ hc,         // [2][64][16]
    int s0, int s1, int tid, int bid)
{
    const int t  = tid & 15;
    const int b4 = tid >> 4;
    const int b  = bid * 4 + b4;

    float wi[16], wf[16], wg[16], wo[16];
#pragma unroll
    for (int k = 0; k < 16; ++k) {
        wi[k] = Whh[(0 * 16 + t) * 16 + k];
        wf[k] = Whh[(1 * 16 + t) * 16 + k];
        wg[k] = Whh[(2 * 16 + t) * 16 + k];
        wo[k] = Whh[(3 * 16 + t) * 16 + k];
    }

    float h, c;
    if (s0 == 0) { h = 0.f; c = 0.f; }
    else         { h = hc[b * 16 + t]; c = hc[1024 + b * 16 + t]; }

    // f4 view: element (s,b,t) at f4-index (s*64+b)*16 + t; s-stride = 1024
    const f4* xp = reinterpret_cast<const f4*>(xg) + b * 16 + t;
    f4 xv = xp[(size_t)s0 * 1024];
    for (int s = s0; s < s1; ++s) {
        f4 nx = (s < 127) ? xp[(size_t)(s + 1) * 1024] : (f4)0.f;
        float ai = xv.x, af = xv.y, ag = xv.z, ao = xv.w;
#pragma unroll
        for (int k = 0; k < 16; ++k) {
            float hk = __shfl(h, k, 16);
            ai = fmaf(hk, wi[k], ai);
            af = fmaf(hk, wf[k], af);
            ag = fmaf(hk, wg[k], ag);
            ao = fmaf(hk, wo[k], ao);
        }
        float ig = fsig(ai), fg = fsig(af), og = fsig(ao);
        float gt = ftanh(ag);
        c = fg * c + ig * gt;
        h = og * ftanh(c);
        w[((size_t)s * 64 + b) * 16 + t] = h;
        xv = nx;
    }
    hc[b * 16 + t] = h;
    hc[1024 + b * 16 + t] = c;
}

__global__ __launch_bounds__(64) void scan_kernel(
    const float* __restrict__ xg, const float* __restrict__ Whh,
    float* __restrict__ w, float* __restrict__ hc, int s0, int s1)
{
    scan_chunk(xg, Whh, w, hc, s0, s1, threadIdx.x, blockIdx.x);
}

// ---------------------------------------------------------------------------
// wsum tile: one sequence-step s, one 1024-col tile ct (0-3:A, 4-5:B, 6-8:C).
// 64 rows (the batch dim). w reads are wave-uniform -> scalar path; matrix
// slice (16 f4) in registers; coalesced f4 stores. No LDS, no barriers.
// ---------------------------------------------------------------------------
__device__ __forceinline__ void wsum_tile(
    const float* __restrict__ w,
    const float* __restrict__ As, const float* __restrict__ Bs,
    const float* __restrict__ Cs,
    float* __restrict__ outA, float* __restrict__ outB, float* __restrict__ outC,
    int s, int ct, int tid)
{
    const float* M; float* o; int C, cto;
    if (ct < 4)      { M = As; o = outA; C = 4096; cto = ct; }
    else if (ct < 6) { M = Bs; o = outB; C = 2048; cto = ct - 4; }
    else             { M = Cs; o = outC; C = 3072; cto = ct - 6; }
    const int i4 = cto * 1024 + tid * 4;

    f4 m[16];
#pragma unroll
    for (int k = 0; k < 16; ++k)
        m[k] = *reinterpret_cast<const f4*>(&M[(size_t)k * C + i4]);

    const float* wp = w + (size_t)s * 1024;   // wave-uniform
    float* op = o + (size_t)(s * 64) * C + i4;

#pragma unroll 2
    for (int r = 0; r < 64; ++r) {
        f4 acc = (f4)0.f;
#pragma unroll
        for (int k = 0; k < 16; ++k)
            acc += wp[r * 16 + k] * m[k];     // uniform -> s_load
        *reinterpret_cast<f4*>(op) = acc;
        op += C;
    }
}

__global__ __launch_bounds__(256) void wsum_kernel(
    const float* __restrict__ w,
    const float* __restrict__ As, const float* __restrict__ Bs,
    const float* __restrict__ Cs,
    float* __restrict__ outA, float* __restrict__ outB, float* __restrict__ outC,
    int sBase)
{
    wsum_tile(w, As, Bs, Cs, outA, outB, outC,
              sBase + blockIdx.x / 9, blockIdx.x % 9, threadIdx.x);
}

// Fused: blocks 0-15 run scan steps [64,128); blocks 16.. run wsum s in [0,64).
// No dependency between the two halves; w[0..64) came from the previous
// dispatch (kernel-boundary ordering). No flags, no spin.
__global__ __launch_bounds__(256) void fused_scanB_wsumA_kernel(
    const float* __restrict__ xg, const float* __restrict__ Whh,
    float* __restrict__ w, float* __restrict__ hc,
    const float* __restrict__ As, const float* __restrict__ Bs,
    const float* __restrict__ Cs,
    float* __restrict__ outA, float* __restrict__ outB, float* __restrict__ outC)
{
    const int bid = blockIdx.x;
    if (bid < 16) {
        if (threadIdx.x >= 64) return;   // 1 scan wave; no barriers anywhere
        scan_chunk(xg, Whh, w, hc, 64, 128, threadIdx.x, bid);
        return;
    }
    const int j = bid - 16;
    wsum_tile(w, As, Bs, Cs, outA, outB, outC, j / 9, j % 9, threadIdx.x);
}

// ---------------------------------------------------------------------------
extern "C" void kernel_launch(void* const* d_in, const int* in_sizes, int n_in,
                              void* d_out, int out_size, void* d_ws, size_t ws_size,
                              hipStream_t stream) {
    const float* state = (const float*)d_in[0];
    const float* W_ih  = (const float*)d_in[1];
    const float* W_hh  = (const float*)d_in[2];
    const float* b_ih  = (const float*)d_in[3];
    const float* b_hh  = (const float*)d_in[4];
    const float* As    = (const float*)d_in[5];
    const float* Bs    = (const float*)d_in[6];
    const float* Cs    = (const float*)d_in[7];
    float* out = (float*)d_out;

    float* xg = (float*)d_ws;                 // 8192*64 floats = 2 MiB
    float* w  = xg + (size_t)SB * 64;         // 8192*16 floats = 512 KiB
    float* hc = w + (size_t)SB * 16;          // 2*64*16 floats = 8 KiB

    float* outA = out;
    float* outB = out + (size_t)SB * 4096;
    float* outC = out + (size_t)SB * 4096 + (size_t)SB * 2048;

    xgate_kernel<<<SB / 4, 256, 0, stream>>>(state, W_ih, b_ih, b_hh, xg);
    scan_kernel<<<16, 64, 0, stream>>>(xg, W_hh, w, hc, 0, 64);
    fused_scanB_wsumA_kernel<<<16 + 576, 256, 0, stream>>>(xg, W_hh, w, hc,
                                                           As, Bs, Cs, outA, outB, outC);
    wsum_kernel<<<576, 256, 0, stream>>>(w, As, Bs, Cs, outA, outB, outC, 64);
}

// Round 9
// 124.025 us; speedup vs baseline: 15.2360x; 1.1007x over previous
//
#include <hip/hip_runtime.h>
#include <hip/hip_bf16.h>

// Sizes: S=128, B=64, N=64, K=16, P=48, M=32
// Outputs: A [S,B,64,64] (C=4096), Bo [S,B,64,32] (C=2048), Cc [S,B,48,64] (C=3072)
#define SB 8192   // S*B

typedef float f4 __attribute__((ext_vector_type(4)));  // clang-native vec4

__device__ __forceinline__ float fsig(float x) {
    return __builtin_amdgcn_rcpf(1.f + __expf(-x));
}
__device__ __forceinline__ float ftanh(float x) {
    // tanh(x) = 1 - 2/(exp(2x)+1); correct limits at +-inf via rcp(inf)=0
    return fmaf(-2.f, __builtin_amdgcn_rcpf(1.f + __expf(2.f * x)), 1.f);
}

// ---------------------------------------------------------------------------
// Kernel 1: xg[row][t*4+q] = dot(x[row], W_ih[q*16+t]) + b_ih[g] + b_hh[g]
// Gate-interleaved layout so the scan loads one float4 per step.
// ---------------------------------------------------------------------------
__global__ __launch_bounds__(256) void xgate_kernel(
    const float* __restrict__ x,    // [8192][64]
    const float* __restrict__ Wih,  // [64][64]
    const float* __restrict__ bih,  // [64]
    const float* __restrict__ bhh,  // [64]
    float* __restrict__ xg)         // [8192][16][4] gate-interleaved
{
    __shared__ float xs[4][64];
    const int tid = threadIdx.x;
    const int rl  = tid >> 6;
    const int g   = tid & 63;           // weight row: g = q*16 + t
    const size_t rowBase = (size_t)blockIdx.x * 4;

    xs[rl][g] = x[rowBase * 64 + tid];
    __syncthreads();

    const float* xr = xs[rl];
    float acc = bih[g] + bhh[g];
#pragma unroll
    for (int n = 0; n < 64; n += 4) {
        f4 wv = *reinterpret_cast<const f4*>(&Wih[g * 64 + n]);
        acc = fmaf(xr[n + 0], wv.x, acc);
        acc = fmaf(xr[n + 1], wv.y, acc);
        acc = fmaf(xr[n + 2], wv.z, acc);
        acc = fmaf(xr[n + 3], wv.w, acc);
    }
    // remap: unit t = g&15, gate q = g>>4  ->  slot t*4+q
    xg[(rowBase + rl) * 64 + (g & 15) * 4 + (g >> 4)] = acc;
}

// ---------------------------------------------------------------------------
// Kernel 2: sequential LSTM scan, 16 blocks x 1 wave; thread owns (b, t).
// h broadcast via width-16 shfl (no LDS, no barriers).
// KEY CHANGE vs R6: 8-deep register prefetch of the per-step xg float4 —
// xg is remote-XCD/HBM (~700-900 cyc); 1-step prefetch exposed ~700 cyc/step
// on the serial chain. 8 steps x ~190 cyc work > latency -> fully hidden.
// ---------------------------------------------------------------------------
__global__ __launch_bounds__(64) void lstm_scan_kernel(
    const float* __restrict__ xg,   // [S][B][16][4]
    const float* __restrict__ Whh,  // [64][16]
    float* __restrict__ w)          // [S][B][16]
{
    const int tid = threadIdx.x;
    const int t  = tid & 15;
    const int b  = blockIdx.x * 4 + (tid >> 4);

    float wi[16], wf[16], wg[16], wo[16];
#pragma unroll
    for (int k = 0; k < 16; ++k) {
        wi[k] = Whh[(0 * 16 + t) * 16 + k];
        wf[k] = Whh[(1 * 16 + t) * 16 + k];
        wg[k] = Whh[(2 * 16 + t) * 16 + k];
        wo[k] = Whh[(3 * 16 + t) * 16 + k];
    }

    // f4 view: element (s,b,t) at f4-index (s*64+b)*16 + t; s-stride = 1024
    const f4* xp = reinterpret_cast<const f4*>(xg) + b * 16 + t;

    // prime the 8-deep pipeline (statically indexed -> stays in VGPRs)
    f4 pf[8];
#pragma unroll
    for (int i = 0; i < 8; ++i) pf[i] = xp[(size_t)i * 1024];

    float h = 0.f, c = 0.f;
    for (int s = 0; s < 128; s += 8) {
#pragma unroll
        for (int u = 0; u < 8; ++u) {
            f4 xv = pf[u];
            // refill 8 steps ahead (guarded; static index u)
            if (s + u + 8 < 128) pf[u] = xp[(size_t)(s + u + 8) * 1024];

            float ai = xv.x, af = xv.y, ag = xv.z, ao = xv.w;
#pragma unroll
            for (int k = 0; k < 16; ++k) {
                float hk = __shfl(h, k, 16);
                ai = fmaf(hk, wi[k], ai);
                af = fmaf(hk, wf[k], af);
                ag = fmaf(hk, wg[k], ag);
                ao = fmaf(hk, wo[k], ao);
            }
            float ig = fsig(ai), fg = fsig(af), og = fsig(ao);
            float gt = ftanh(ag);
            c = fg * c + ig * gt;
            h = og * ftanh(c);
            w[((size_t)(s + u) * 64 + b) * 16 + t] = h;
        }
    }
}

// ---------------------------------------------------------------------------
// Kernel 3 (merged, identical to R6): out[row][i] = sum_k w[row][k]*M[k][i].
// Block = 256 threads x f4 = 1024 cols, 32 rows. 2304 blocks = 9/CU exactly.
// w rows wave-uniform -> scalar s_load path; m[16] in registers; plain
// coalesced f4 stores. No LDS, no barriers.
// ---------------------------------------------------------------------------
__global__ __launch_bounds__(256) void wsum_all_kernel(
    const float* __restrict__ w,   // [8192][16]
    const float* __restrict__ As, const float* __restrict__ Bs,
    const float* __restrict__ Cs,
    float* __restrict__ outA, float* __restrict__ outB, float* __restrict__ outC)
{
    const int tid = threadIdx.x;
    const int bid = blockIdx.x;

    const float* M; float* o; int C, local, colTiles;
    if (bid < 1024)      { M = As; o = outA; C = 4096; local = bid;        colTiles = 4; }
    else if (bid < 1536) { M = Bs; o = outB; C = 2048; local = bid - 1024; colTiles = 2; }
    else                 { M = Cs; o = outC; C = 3072; local = bid - 1536; colTiles = 3; }

    const int colTile  = local % colTiles;
    const int rowStart = (local / colTiles) * 32;
    const int i4 = colTile * 1024 + tid * 4;

    f4 m[16];
#pragma unroll
    for (int k = 0; k < 16; ++k)
        m[k] = *reinterpret_cast<const f4*>(&M[(size_t)k * C + i4]);

    const float* wp = w + (size_t)rowStart * 16;   // wave-uniform
    float* op = o + (size_t)rowStart * C + i4;

#pragma unroll 2
    for (int r = 0; r < 32; ++r) {
        f4 acc = (f4)0.f;
#pragma unroll
        for (int k = 0; k < 16; ++k)
            acc += wp[r * 16 + k] * m[k];          // uniform -> s_load
        *reinterpret_cast<f4*>(op) = acc;
        op += C;
    }
}

// ---------------------------------------------------------------------------
extern "C" void kernel_launch(void* const* d_in, const int* in_sizes, int n_in,
                              void* d_out, int out_size, void* d_ws, size_t ws_size,
                              hipStream_t stream) {
    const float* state = (const float*)d_in[0];
    const float* W_ih  = (const float*)d_in[1];
    const float* W_hh  = (const float*)d_in[2];
    const float* b_ih  = (const float*)d_in[3];
    const float* b_hh  = (const float*)d_in[4];
    const float* As    = (const float*)d_in[5];
    const float* Bs    = (const float*)d_in[6];
    const float* Cs    = (const float*)d_in[7];
    float* out = (float*)d_out;

    float* xg = (float*)d_ws;            // 8192*64 floats
    float* w  = xg + (size_t)SB * 64;    // 8192*16 floats

    xgate_kernel<<<SB / 4, 256, 0, stream>>>(state, W_ih, b_ih, b_hh, xg);
    lstm_scan_kernel<<<16, 64, 0, stream>>>(xg, W_hh, w);

    float* outA = out;
    float* outB = out + (size_t)SB * 4096;
    float* outC = out + (size_t)SB * 4096 + (size_t)SB * 2048;

    wsum_all_kernel<<<2304, 256, 0, stream>>>(w, As, Bs, Cs, outA, outB, outC);
}

// Round 10
// 123.558 us; speedup vs baseline: 15.2937x; 1.0038x over previous
//
#include <hip/hip_runtime.h>
#include <hip/hip_bf16.h>

// Sizes: S=128, B=64, N=64, K=16, P=48, M=32
// Outputs: A [S,B,64,64] (C=4096), Bo [S,B,64,32] (C=2048), Cc [S,B,48,64] (C=3072)
#define SB 8192   // S*B

typedef float f4 __attribute__((ext_vector_type(4)));  // clang-native vec4

__device__ __forceinline__ float fsig(float x) {
    return __builtin_amdgcn_rcpf(1.f + __expf(-x));
}
__device__ __forceinline__ float ftanh(float x) {
    // tanh(x) = 1 - 2/(exp(2x)+1); correct limits at +-inf via rcp(inf)=0
    return fmaf(-2.f, __builtin_amdgcn_rcpf(1.f + __expf(2.f * x)), 1.f);
}

// ---------------------------------------------------------------------------
// Kernel 1 (identical to R6): xg[row][t*4+q] = dot(x[row], W_ih[q*16+t]) + b.
// Gate-interleaved: f4 #t of each row holds the 4 gate pre-activations of
// hidden unit t.
// ---------------------------------------------------------------------------
__global__ __launch_bounds__(256) void xgate_kernel(
    const float* __restrict__ x,    // [8192][64]
    const float* __restrict__ Wih,  // [64][64]
    const float* __restrict__ bih,  // [64]
    const float* __restrict__ bhh,  // [64]
    float* __restrict__ xg)         // [8192][16][4] gate-interleaved
{
    __shared__ float xs[4][64];
    const int tid = threadIdx.x;
    const int rl  = tid >> 6;
    const int g   = tid & 63;           // weight row: g = q*16 + t
    const size_t rowBase = (size_t)blockIdx.x * 4;

    xs[rl][g] = x[rowBase * 64 + tid];
    __syncthreads();

    const float* xr = xs[rl];
    float acc = bih[g] + bhh[g];
#pragma unroll
    for (int n = 0; n < 64; n += 4) {
        f4 wv = *reinterpret_cast<const f4*>(&Wih[g * 64 + n]);
        acc = fmaf(xr[n + 0], wv.x, acc);
        acc = fmaf(xr[n + 1], wv.y, acc);
        acc = fmaf(xr[n + 2], wv.z, acc);
        acc = fmaf(xr[n + 3], wv.w, acc);
    }
    // remap: unit t = g&15, gate q = g>>4  ->  slot t*4+q
    xg[(rowBase + rl) * 64 + (g & 15) * 4 + (g >> 4)] = acc;
}

// ---------------------------------------------------------------------------
// Kernel 2 (NEW): producer/consumer staged LSTM scan. 16 blocks x 256 thr.
// Waves 1-3 stream xg into a double-buffered LDS pipeline (16-step chunks);
// wave 0 scans purely from LDS -> serial chain sees ~60cyc LDS latency, not
// ~700cyc remote-L2/HBM. Scan runtime bounded by construction (~12 us).
// ---------------------------------------------------------------------------
__global__ __launch_bounds__(256) void lstm_scan_staged_kernel(
    const float* __restrict__ xg,   // [S][B][16][4]  (f4 idx: row*16 + t)
    const float* __restrict__ Whh,  // [64][16]
    float* __restrict__ w)          // [S][B][16]
{
    // buf[c][ss][bb][t] : 16 steps x 4 batches x 16 units (f4 each) = 16 KB
    __shared__ f4 buf[2][1024];
    const int tid  = threadIdx.x;
    const int wave = tid >> 6;
    const int b0   = blockIdx.x * 4;
    const f4* xgf4 = reinterpret_cast<const f4*>(xg);

    // consumer state (wave 0 only)
    float wi[16], wf[16], wg[16], wo[16];
    const int t  = tid & 15;
    const int bb = (tid >> 4) & 3;
    if (wave == 0) {
#pragma unroll
        for (int k = 0; k < 16; ++k) {
            wi[k] = Whh[(0 * 16 + t) * 16 + k];
            wf[k] = Whh[(1 * 16 + t) * 16 + k];
            wg[k] = Whh[(2 * 16 + t) * 16 + k];
            wo[k] = Whh[(3 * 16 + t) * 16 + k];
        }
    } else {
        // producers: prologue-load chunk 0 into buf[0]
        const int lane = tid - 64;                 // 0..191
        for (int j = lane; j < 1024; j += 192)
            buf[0][j] = xgf4[(size_t)(j >> 6) * 1024 + b0 * 16 + (j & 63)];
    }
    __syncthreads();   // buf[0] ready

    float h = 0.f, c = 0.f;
    for (int chunk = 0; chunk < 8; ++chunk) {
        if (wave == 0) {
            // ---- consumer: scan 16 steps from buf[chunk&1] ----
            const f4* xb = &buf[chunk & 1][bb * 16 + t];   // step stride 64 f4
#pragma unroll
            for (int u = 0; u < 16; ++u) {
                f4 xv = xb[u * 64];
                float ai = xv.x, af = xv.y, ag = xv.z, ao = xv.w;
#pragma unroll
                for (int k = 0; k < 16; ++k) {
                    float hk = __shfl(h, k, 16);
                    ai = fmaf(hk, wi[k], ai);
                    af = fmaf(hk, wf[k], af);
                    ag = fmaf(hk, wg[k], ag);
                    ao = fmaf(hk, wo[k], ao);
                }
                float ig = fsig(ai), fg = fsig(af), og = fsig(ao);
                float gt = ftanh(ag);
                c = fg * c + ig * gt;
                h = og * ftanh(c);
                // fire-and-forget store; nothing ever waits on it
                w[((size_t)(chunk * 16 + u) * 64 + (b0 + bb)) * 16 + t] = h;
            }
        } else if (chunk + 1 < 8) {
            // ---- producers: load chunk+1 into the other buffer ----
            const int lane = tid - 64;
            f4* dst = buf[(chunk + 1) & 1];
            const size_t base = (size_t)(chunk + 1) * 16 * 1024 + b0 * 16;
            for (int j = lane; j < 1024; j += 192)
                dst[j] = xgf4[base + (size_t)(j >> 6) * 1024 + (j & 63)];
        }
        __syncthreads();   // next buffer ready; safe to overwrite the read one
    }
}

// ---------------------------------------------------------------------------
// Kernel 3 (identical to R6): out[row][i] = sum_k w[row][k]*M[k][i].
// Block = 256 threads x f4 = 1024 cols, 32 rows. 2304 blocks.
// w rows wave-uniform -> scalar s_load path; m[16] in registers; plain
// coalesced f4 stores. No LDS, no barriers.
// ---------------------------------------------------------------------------
__global__ __launch_bounds__(256) void wsum_all_kernel(
    const float* __restrict__ w,   // [8192][16]
    const float* __restrict__ As, const float* __restrict__ Bs,
    const float* __restrict__ Cs,
    float* __restrict__ outA, float* __restrict__ outB, float* __restrict__ outC)
{
    const int tid = threadIdx.x;
    const int bid = blockIdx.x;

    const float* M; float* o; int C, local, colTiles;
    if (bid < 1024)      { M = As; o = outA; C = 4096; local = bid;        colTiles = 4; }
    else if (bid < 1536) { M = Bs; o = outB; C = 2048; local = bid - 1024; colTiles = 2; }
    else                 { M = Cs; o = outC; C = 3072; local = bid - 1536; colTiles = 3; }

    const int colTile  = local % colTiles;
    const int rowStart = (local / colTiles) * 32;
    const int i4 = colTile * 1024 + tid * 4;

    f4 m[16];
#pragma unroll
    for (int k = 0; k < 16; ++k)
        m[k] = *reinterpret_cast<const f4*>(&M[(size_t)k * C + i4]);

    const float* wp = w + (size_t)rowStart * 16;   // wave-uniform
    float* op = o + (size_t)rowStart * C + i4;

#pragma unroll 2
    for (int r = 0; r < 32; ++r) {
        f4 acc = (f4)0.f;
#pragma unroll
        for (int k = 0; k < 16; ++k)
            acc += wp[r * 16 + k] * m[k];          // uniform -> s_load
        *reinterpret_cast<f4*>(op) = acc;
        op += C;
    }
}

// ---------------------------------------------------------------------------
extern "C" void kernel_launch(void* const* d_in, const int* in_sizes, int n_in,
                              void* d_out, int out_size, void* d_ws, size_t ws_size,
                              hipStream_t stream) {
    const float* state = (const float*)d_in[0];
    const float* W_ih  = (const float*)d_in[1];
    const float* W_hh  = (const float*)d_in[2];
    const float* b_ih  = (const float*)d_in[3];
    const float* b_hh  = (const float*)d_in[4];
    const float* As    = (const float*)d_in[5];
    const float* Bs    = (const float*)d_in[6];
    const float* Cs    = (const float*)d_in[7];
    float* out = (float*)d_out;

    float* xg = (float*)d_ws;            // 8192*64 floats
    float* w  = xg + (size_t)SB * 64;    // 8192*16 floats

    xgate_kernel<<<SB / 4, 256, 0, stream>>>(state, W_ih, b_ih, b_hh, xg);
    lstm_scan_staged_kernel<<<16, 256, 0, stream>>>(xg, W_hh, w);

    float* outA = out;
    float* outB = out + (size_t)SB * 4096;
    float* outC = out + (size_t)SB * 4096 + (size_t)SB * 2048;

    wsum_all_kernel<<<2304, 256, 0, stream>>>(w, As, Bs, Cs, outA, outB, outC);
}